// Round 1
// 190.691 us; speedup vs baseline: 1.0112x; 1.0112x over previous
//
#include <hip/hip_runtime.h>
#include <hip/hip_bf16.h>

#define NB 2
#define NT 2048
#define ND 1024
#define NHEADS 16
#define NKVH 4
#define HDIM 64
#define QKVD 1536   // (NHEADS + 2*NKVH) * HDIM

typedef __attribute__((ext_vector_type(8))) short short8;
typedef __attribute__((ext_vector_type(4))) float floatx4;

#if defined(__has_builtin)
#  if __has_builtin(__builtin_amdgcn_global_load_lds)
#    define HAS_GLL 1
#  endif
#endif
#ifndef HAS_GLL
#  define HAS_GLL 0
#endif

// async global->LDS, 16B per lane (wave-uniform base + lane*16).
__device__ __forceinline__ void gll16(const void* g, void* l, int lane) {
#if HAS_GLL
  (void)lane;
  __builtin_amdgcn_global_load_lds(
      (const __attribute__((address_space(1))) unsigned int*)g,
      (__attribute__((address_space(3))) unsigned int*)l, 16, 0, 0);
#else
  *(short8*)((short*)l) = *(const short8*)g;
#endif
}

__device__ __forceinline__ unsigned short f2bf(float f) {
  union { float f; unsigned int u; } cv; cv.f = f;
  unsigned int u = cv.u;
  u += 0x7fffu + ((u >> 16) & 1u);   // round-to-nearest-even
  return (unsigned short)(u >> 16);
}
__device__ __forceinline__ float bf2f(unsigned short u) {
  union { unsigned int u; float f; } cv; cv.u = ((unsigned int)u) << 16; return cv.f;
}

// ------------------------------------------- one fused fp32->bf16 convert pass
#define N4_X   1048576   // NB*NT*ND/4
#define N4_WQ   393216   // QKVD*ND/4
#define N4_WO   262144   // ND*ND/4
__global__ __launch_bounds__(256) void cvt_all(
    const float* __restrict__ x, const float* __restrict__ wq,
    const float* __restrict__ wo,
    unsigned short* __restrict__ xb, unsigned short* __restrict__ wqb,
    unsigned short* __restrict__ wob) {
  int i = blockIdx.x * 256 + threadIdx.x;
  const float* src; unsigned short* dst; int j;
  if (i < N4_X)              { src = x;  dst = xb;  j = i; }
  else if (i < N4_X + N4_WQ) { src = wq; dst = wqb; j = i - N4_X; }
  else                       { src = wo; dst = wob; j = i - N4_X - N4_WQ; }
  float4 v = ((const float4*)src)[j];
  ushort4 o;
  o.x = f2bf(v.x); o.y = f2bf(v.y); o.z = f2bf(v.z); o.w = f2bf(v.w);
  ((ushort4*)dst)[j] = o;
}

// ============ SINGLE-WAVE GEMM building block: 64x64 tile, GLL + dbuf =======
// One wave per block (64 threads): no inter-wave barrier coupling; 10 blocks/CU
// (16 KB LDS each) provide the latency overlap. 16 MFMA : 8 ds_read_b128 per
// K-step (m97 ratio). Swizzle on gptr side (logical chunk ^ (row&3)).

// staging: GLL group g (0..3) stages rows 16g..16g+15 of a 64x32-short tile.
#define GEMM1W_PROLOGUE(Aptr, Bptr, Kdim)                                      \
  __shared__ __align__(16) short As[2][64][32];                                \
  __shared__ __align__(16) short Bs[2][64][32];                                \
  const int lane = threadIdx.x;                                                \
  const int quad = lane >> 4, l16 = lane & 15;                                 \
  const int srow = lane >> 2;                                                  \
  const int sch  = ((lane & 3) ^ (srow & 3)) * 8;                              \
  const unsigned short* agp = (Aptr) + (size_t)(m0 + srow) * (Kdim) + sch;     \
  const unsigned short* bgp = (Bptr) + (size_t)(n0 + srow) * (Kdim) + sch;     \
  short* asb = &As[0][0][0];                                                   \
  short* bsb = &Bs[0][0][0];                                                   \
  const int lofs = (HAS_GLL ? 0 : lane * 8);                                   \
  const int cs = (quad ^ (l16 & 3)) * 8;                                       \
  floatx4 acc[4][4] = {};                                                      \
  _Pragma("unroll")                                                            \
  for (int g = 0; g < 4; g++) {                                                \
    gll16(agp + (size_t)(16 * g) * (Kdim), asb + g * 512 + lofs, lane);        \
    gll16(bgp + (size_t)(16 * g) * (Kdim), bsb + g * 512 + lofs, lane);        \
  }                                                                            \
  const int NIT = (Kdim) / 32;                                                 \
  for (int it = 0; it < NIT; it++) {                                           \
    __syncthreads();                                                           \
    const int bi = it & 1, bn = bi ^ 1;                                        \
    if (it + 1 < NIT) {                                                        \
      const int k = (it + 1) * 32;                                             \
      _Pragma("unroll")                                                        \
      for (int g = 0; g < 4; g++) {                                            \
        gll16(agp + (size_t)(16 * g) * (Kdim) + k, asb + bn * 2048 + g * 512 + lofs, lane); \
        gll16(bgp + (size_t)(16 * g) * (Kdim) + k, bsb + bn * 2048 + g * 512 + lofs, lane); \
      }                                                                        \
    }                                                                          \
    short8 af[4], bf[4];                                                       \
    _Pragma("unroll")                                                          \
    for (int mi = 0; mi < 4; mi++) af[mi] = *(const short8*)&As[bi][mi * 16 + l16][cs]; \
    _Pragma("unroll")                                                          \
    for (int ni = 0; ni < 4; ni++) bf[ni] = *(const short8*)&Bs[bi][ni * 16 + l16][cs]; \
    _Pragma("unroll")                                                          \
    for (int mi = 0; mi < 4; mi++)                                             \
      _Pragma("unroll")                                                        \
      for (int ni = 0; ni < 4; ni++)                                           \
        acc[mi][ni] = __builtin_amdgcn_mfma_f32_16x16x32_bf16(af[mi], bf[ni], acc[mi][ni], 0, 0, 0); \
  }

// ---------------- QKV GEMM (single-wave) with fused rope/scale/pack epilogue
// Grid (64, 24): blockIdx.y = head slice hh. hh<16 -> q (rope + 0.125*log2e*
// q_scale), 16..19 -> k (rope + k_scale), 20..23 -> v (written transposed).
__global__ __launch_bounds__(64) void gemm_qkv(
    const unsigned short* __restrict__ A,
    const unsigned short* __restrict__ Bm,
    const float* __restrict__ cosT, const float* __restrict__ sinT,
    const float* __restrict__ q_scale, const float* __restrict__ k_scale,
    unsigned short* __restrict__ qb, unsigned short* __restrict__ kb,
    unsigned short* __restrict__ vtb)
{
  const int m0 = blockIdx.x * 64, n0 = blockIdx.y * 64;
  GEMM1W_PROLOGUE(A, Bm, ND)

  const int hh = blockIdx.y;   // block-uniform head slice
  const int lo8 = l16 & 7;

  if (hh >= NHEADS + NKVH) {
    // ---- v: write transposed bf16 to vtb[(b*NKV+kvh)*64 + d][t]
    const int kvh = hh - (NHEADS + NKVH);
#pragma unroll
    for (int mi = 0; mi < 4; mi++) {
      const int mrow = m0 + mi * 16 + quad * 4;
      const int bb = mrow >> 11, tt = mrow & (NT - 1);
#pragma unroll
      for (int ni = 0; ni < 4; ni++) {
        const int d = ni * 16 + l16;
        ushort4 w;
        w.x = f2bf(acc[mi][ni][0]); w.y = f2bf(acc[mi][ni][1]);
        w.z = f2bf(acc[mi][ni][2]); w.w = f2bf(acc[mi][ni][3]);
        *(ushort4*)(vtb + ((size_t)((bb * NKVH + kvh) * HDIM + d)) * NT + tt) = w;
      }
    }
  } else {
    // ---- q/k: rope first 16 dims (ni==0), scale, write head-major bf16
    float scl; unsigned short* dst0; int hloc, nh;
    if (hh < NHEADS) { scl = q_scale[hh] * (0.125f * 1.44269504088896f); hloc = hh; dst0 = qb; nh = NHEADS; }
    else             { scl = k_scale[hh - NHEADS]; hloc = hh - NHEADS; dst0 = kb; nh = NKVH; }
#pragma unroll
    for (int mi = 0; mi < 4; mi++) {
#pragma unroll
      for (int r = 0; r < 4; r++) {
        const int mrow = m0 + mi * 16 + quad * 4 + r;
        const int bb = mrow >> 11, tt = mrow & (NT - 1);
        unsigned short* drow = dst0 + ((size_t)((bb * nh + hloc) * NT + tt)) * HDIM;

        const float own = acc[mi][0][r];
        const float oth = __shfl_xor(own, 8);
        const float c = cosT[tt * 8 + lo8], s = sinT[tt * 8 + lo8];
        const float roped = (l16 < 8) ? (own * c - oth * s)
                                      : (oth * s + own * c);
        drow[l16] = f2bf(roped * scl);
#pragma unroll
        for (int ni = 1; ni < 4; ni++)
          drow[ni * 16 + l16] = f2bf(acc[mi][ni][r] * scl);
      }
    }
  }
}

// ------------- out GEMM (single-wave): C = A * B^T (fp32 C) ------------------
__global__ __launch_bounds__(64) void gemm_out(
    const unsigned short* __restrict__ A,
    const unsigned short* __restrict__ Bm,
    float* __restrict__ C, int M, int N, int K)
{
  const int m0 = blockIdx.x * 64, n0 = blockIdx.y * 64;
  GEMM1W_PROLOGUE(A, Bm, K)

#pragma unroll
  for (int mi = 0; mi < 4; mi++)
#pragma unroll
    for (int ni = 0; ni < 4; ni++)
#pragma unroll
      for (int r = 0; r < 4; r++) {
        int m = m0 + mi * 16 + quad * 4 + r;
        int n = n0 + ni * 16 + l16;
        C[(size_t)m * N + n] = acc[mi][ni][r];
      }
}

// ----------------------------------------------------- flash attention (MFMA)
// r7: swapped QK^T (S^T = mfma(K,Q)) so each lane holds one q-row with 16
// kv-CONSECUTIVE P values -> cvt_pk bf16 pairs + 4x ds_write_b64 (was 16x
// ds_write_b16 + 16x scalar f2bf). lsum is a scalar per lane (q row is
// lane-local); cross-quad reduce moves to the epilogue (2 shfl_xor).
// Otherwise: r6 config, 4 waves x 16 q-rows, GLL-staged dbuf K/V, fixed-m
// base-2 softmax, uniform KV-chunking.
__global__ __launch_bounds__(256) void fattn(
    const unsigned short* __restrict__ qb,   // [B][NH][T][64]
    const unsigned short* __restrict__ kb,   // [B][NKV][T][64]
    const unsigned short* __restrict__ vtb,  // [B][NKV][64][T]
    unsigned short* __restrict__ aob,        // [B][T][NH*64]
    float* __restrict__ pbuf)                // slots x (64*64 O + 64 l) fp32
{
  const int idx = blockIdx.x;
  const int h = blockIdx.y, b = blockIdx.z;
  const int kv = h >> 2;

  int qt, j0, cnt, chunk; bool direct;
  if (idx < 16) { qt = 16 + idx; j0 = 0; cnt = 16; chunk = 0; direct = false; }
  else {
    int rel = idx - 16, s = 16 - (rel >> 1);
    if ((rel & 1) == 0) { qt = s - 1;  j0 = 0;  cnt = s; chunk = 0; direct = true;  }
    else                { qt = s + 15; j0 = 16; cnt = s; chunk = 1; direct = false; }
  }

  const int tid = threadIdx.x;
  const int wid = tid >> 6, lane = tid & 63;
  const int quad = lane >> 4, l16 = lane & 15;
  const int lo8 = l16 & 7;

  __shared__ __align__(16) short Ks[2][64][64];   // [t][d], chunk^(t&7) via gptr
  __shared__ __align__(16) short Vs[2][64][64];   // [d][t], chunk^(d&7) via gptr
  __shared__ __align__(16) short Ps[4][16][64];   // [wave][q][kv], 16B-chunk ^ (q&7)

  const unsigned short* qg = qb + ((size_t)((b * NHEADS + h) * NT + qt * 64)) * HDIM;
  const int qrow = wid * 16 + l16;
  short8 aq0 = *(const short8*)(qg + (size_t)qrow * HDIM + quad * 8);
  short8 aq1 = *(const short8*)(qg + (size_t)qrow * HDIM + 32 + quad * 8);

  const int sr  = tid >> 3;
  const int lck = ((tid & 7) ^ (sr & 7)) * 8;
  const unsigned short* kgp0 = kb  + ((size_t)((b * NKVH + kv) * NT) + sr) * HDIM + lck;
  const unsigned short* vgp0 = vtb + ((size_t)((b * NKVH + kv) * HDIM) + sr) * NT + lck;
  short* ksb = &Ks[0][0][0];
  short* vsb = &Vs[0][0][0];
  const int lofs = (HAS_GLL ? wid * 512 : tid * 8);

  const int cs0 = (quad ^ lo8) * 8;
  const int cs1 = cs0 ^ 32;

  // P scratch addressing (byte offsets into Ps):
  //   logical u32 column u = kv/2 = nb*8 + 2*quad + h   (h = pair index 0/1)
  //   16B chunk cc = u>>2 = 2*nb + (quad>>1), stored at cc ^ (l16&7)
  //   write: b64 covers u = {nb*8+2q, +1} -> in-chunk byte (quad&1)*8
  //   read (PV A-frag): lane needs kv 8*quad..+7 = chunk quad (ap0) / 4+quad (ap1)
  char* psb = (char*)&Ps[0][0][0];
  int psw[4];
#pragma unroll
  for (int nb = 0; nb < 4; nb++)
    psw[nb] = wid * 2048 + l16 * 128 +
              ((((nb << 1) | (quad >> 1)) ^ lo8) << 4) + ((quad & 1) << 3);
  const int pr0 = wid * 2048 + l16 * 128 + ((quad ^ lo8) << 4);

  floatx4 acc_o[4] = {};
  float lsum = 0.f;

  {
    const unsigned short* kg = kgp0 + (size_t)j0 * 64 * HDIM;
    const unsigned short* vg = vgp0 + j0 * 64;
    gll16(kg, ksb + lofs, lane);
    gll16(kg + 32 * HDIM, ksb + 2048 + lofs, lane);
    gll16(vg, vsb + lofs, lane);
    gll16(vg + (size_t)32 * NT, vsb + 2048 + lofs, lane);
  }

  for (int i = 0; i < cnt; i++) {
    const int jt = j0 + i;
    __syncthreads();
    const int bi = i & 1, bn = bi ^ 1;
    if (i + 1 < cnt) {
      const unsigned short* kg = kgp0 + (size_t)(jt + 1) * 64 * HDIM;
      const unsigned short* vg = vgp0 + (jt + 1) * 64;
      gll16(kg, ksb + bn * 4096 + lofs, lane);
      gll16(kg + 32 * HDIM, ksb + bn * 4096 + 2048 + lofs, lane);
      gll16(vg, vsb + bn * 4096 + lofs, lane);
      gll16(vg + (size_t)32 * NT, vsb + bn * 4096 + 2048 + lofs, lane);
    }

    // S^T = K * Q^T : lane holds S[q = wid*16+l16][kv = nb*16 + quad*4 + r]
    floatx4 s[4] = {};
#pragma unroll
    for (int nb = 0; nb < 4; nb++) {
      short8 bk0 = *(const short8*)&Ks[bi][nb * 16 + l16][cs0];
      short8 bk1 = *(const short8*)&Ks[bi][nb * 16 + l16][cs1];
      s[nb] = __builtin_amdgcn_mfma_f32_16x16x32_bf16(bk0, aq0, s[nb], 0, 0, 0);
      s[nb] = __builtin_amdgcn_mfma_f32_16x16x32_bf16(bk1, aq1, s[nb], 0, 0, 0);
    }

    if (jt == qt) {
      const int qloc = wid * 16 + l16;
#pragma unroll
      for (int nb = 0; nb < 4; nb++)
#pragma unroll
        for (int r = 0; r < 4; r++)
          if (nb * 16 + quad * 4 + r > qloc) s[nb][r] = -INFINITY;
    }

#pragma unroll
    for (int nb = 0; nb < 4; nb++) {
      float p0 = __builtin_amdgcn_exp2f(s[nb][0]);
      float p1 = __builtin_amdgcn_exp2f(s[nb][1]);
      float p2 = __builtin_amdgcn_exp2f(s[nb][2]);
      float p3 = __builtin_amdgcn_exp2f(s[nb][3]);
      lsum += (p0 + p1) + (p2 + p3);
      unsigned int pk0, pk1;
      asm("v_cvt_pk_bf16_f32 %0, %1, %2" : "=v"(pk0) : "v"(p0), "v"(p1));
      asm("v_cvt_pk_bf16_f32 %0, %1, %2" : "=v"(pk1) : "v"(p2), "v"(p3));
      uint2 w; w.x = pk0; w.y = pk1;
      *(uint2*)(psb + psw[nb]) = w;
    }

    short8 ap0 = *(const short8*)(psb + pr0);
    short8 ap1 = *(const short8*)(psb + (pr0 ^ 64));
#pragma unroll
    for (int nb = 0; nb < 4; nb++) {
      short8 bv0 = *(const short8*)&Vs[bi][nb * 16 + l16][cs0];
      short8 bv1 = *(const short8*)&Vs[bi][nb * 16 + l16][cs1];
      acc_o[nb] = __builtin_amdgcn_mfma_f32_16x16x32_bf16(ap0, bv0, acc_o[nb], 0, 0, 0);
      acc_o[nb] = __builtin_amdgcn_mfma_f32_16x16x32_bf16(ap1, bv1, acc_o[nb], 0, 0, 0);
    }
  }

  const int bl = (cnt - 1) & 1;

  // lsum holds this lane's kv-subset partial for q = wid*16 + l16;
  // cross-quad reduce gives the full row sum in every lane.
  float lst = lsum;
  lst += __shfl_xor(lst, 16);
  lst += __shfl_xor(lst, 32);

  if (direct) {
#pragma unroll
    for (int r = 0; r < 4; r++) {
      const int rowl = wid * 16 + quad * 4 + r;
      const float invl = 1.f / __shfl(lst, quad * 4 + r);

      const int vcol = ((rowl >> 3) ^ lo8) * 8 + (rowl & 7);
      float vd[4], dot = 0.f, vv = 0.f;
#pragma unroll
      for (int nb = 0; nb < 4; nb++) {
        vd[nb] = bf2f((unsigned short)Vs[bl][nb * 16 + l16][vcol]);
        dot += acc_o[nb][r] * invl * vd[nb];
        vv  += vd[nb] * vd[nb];
      }
#pragma unroll
      for (int off = 1; off < 16; off <<= 1) {
        dot += __shfl_xor(dot, off);
        vv  += __shfl_xor(vv, off);
      }
      const float coef = dot / fmaxf(vv, 1e-8f);
      unsigned short* dst = aob + ((size_t)(b * NT + qt * 64 + rowl)) * ND + h * HDIM + l16;
#pragma unroll
      for (int nb = 0; nb < 4; nb++)
        dst[nb * 16] = f2bf(acc_o[nb][r] * invl - coef * vd[nb]);
    }
  } else {
    const int slot = ((b * NHEADS + h) * 16 + (qt - 16)) * 2 + chunk;
    float* pO = pbuf + (size_t)slot * 4160;
    float* pl = pO + 4096;
    if (quad == 0) pl[wid * 16 + l16] = lst;
#pragma unroll
    for (int r = 0; r < 4; r++) {
      const int rowl = wid * 16 + quad * 4 + r;
#pragma unroll
      for (int nb = 0; nb < 4; nb++)
        pO[rowl * 64 + nb * 16 + l16] = acc_o[nb][r];
    }
  }
}

// --------------- reduction for qt>=16: sum 2 partials, normalize, v-orth, store
__global__ __launch_bounds__(256) void redn(
    const float* __restrict__ pbuf,
    const unsigned short* __restrict__ vtb,
    unsigned short* __restrict__ aob)
{
  const int qt = 16 + blockIdx.x;
  const int h = blockIdx.y, b = blockIdx.z;
  const int kv = h >> 2;
  const int tid = threadIdx.x;

  const int slot0 = ((b * NHEADS + h) * 16 + blockIdx.x) * 2;
  const float* O0 = pbuf + (size_t)slot0 * 4160;
  const float* O1 = O0 + 4160;
  const float* l0 = O0 + 4096;
  const float* l1 = O1 + 4096;

  __shared__ short vt[64][66];

  {
    const int d = tid >> 2, tq = (tid & 3) * 16;
    const unsigned short* src = vtb + ((size_t)((b * NKVH + kv) * HDIM + d)) * NT + qt * 64 + tq;
    short8 v0 = *(const short8*)src;
    short8 v1 = *(const short8*)(src + 8);
    *(short8*)&vt[d][tq] = v0;
    *(short8*)&vt[d][tq + 8] = v1;
  }
  __syncthreads();

  const int row = tid >> 2, dq = tid & 3;
  const float invl = 1.f / (l0[row] + l1[row]);

  float o[16], vd[16];
  float dot = 0.f, vv = 0.f;
#pragma unroll
  for (int j = 0; j < 16; j++) {
    const int d = dq * 16 + j;
    float ov = (O0[row * 64 + d] + O1[row * 64 + d]) * invl;
    float v  = bf2f((unsigned short)vt[d][row]);
    o[j] = ov; vd[j] = v;
    dot += ov * v; vv += v * v;
  }
  dot += __shfl_xor(dot, 1); dot += __shfl_xor(dot, 2);
  vv  += __shfl_xor(vv, 1);  vv  += __shfl_xor(vv, 2);
  const float coef = dot / fmaxf(vv, 1e-8f);

  unsigned short* dst = aob + ((size_t)(b * NT + qt * 64 + row)) * ND + h * HDIM + dq * 16;
  ushort4 w0, w1, w2, w3;
  w0.x = f2bf(o[0] - coef * vd[0]);  w0.y = f2bf(o[1] - coef * vd[1]);
  w0.z = f2bf(o[2] - coef * vd[2]);  w0.w = f2bf(o[3] - coef * vd[3]);
  w1.x = f2bf(o[4] - coef * vd[4]);  w1.y = f2bf(o[5] - coef * vd[5]);
  w1.z = f2bf(o[6] - coef * vd[6]);  w1.w = f2bf(o[7] - coef * vd[7]);
  w2.x = f2bf(o[8] - coef * vd[8]);  w2.y = f2bf(o[9] - coef * vd[9]);
  w2.z = f2bf(o[10] - coef * vd[10]); w2.w = f2bf(o[11] - coef * vd[11]);
  w3.x = f2bf(o[12] - coef * vd[12]); w3.y = f2bf(o[13] - coef * vd[13]);
  w3.z = f2bf(o[14] - coef * vd[14]); w3.w = f2bf(o[15] - coef * vd[15]);
  ((ushort4*)dst)[0] = w0; ((ushort4*)dst)[1] = w1;
  ((ushort4*)dst)[2] = w2; ((ushort4*)dst)[3] = w3;
}

// ---------------------------------------------------------------------- launch
extern "C" void kernel_launch(void* const* d_in, const int* in_sizes, int n_in,
                              void* d_out, int out_size, void* d_ws, size_t ws_size,
                              hipStream_t stream) {
  const float* x       = (const float*)d_in[0];
  const float* cosT    = (const float*)d_in[1];
  const float* sinT    = (const float*)d_in[2];
  const float* w_qkv   = (const float*)d_in[4];
  const float* w_out   = (const float*)d_in[5];
  const float* q_scale = (const float*)d_in[6];
  const float* k_scale = (const float*)d_in[7];
  float* out = (float*)d_out;

  // layout (bytes). pbuf (17 MB) overlays xb+wqkvb (dead after gemm_qkv).
  char* ws = (char*)d_ws;
  unsigned short* xb    = (unsigned short*)ws;                   // 0      .. 8 MB
  unsigned short* wqkvb = (unsigned short*)(ws + 8388608);       // 8 MB   .. 11 MB
  float*          pbuf  = (float*)ws;                            // 0      .. 17 MB (overlay)
  unsigned short* woutb = (unsigned short*)(ws + 17825792);      // 17 MB  .. 19 MB
  unsigned short* qb    = (unsigned short*)(ws + 19922944);      // 19 MB  .. 27 MB
  unsigned short* kb    = (unsigned short*)(ws + 28311552);      // 27 MB  .. 29 MB
  unsigned short* vtb   = (unsigned short*)(ws + 30408704);      // 29 MB  .. 31 MB
  unsigned short* aob   = (unsigned short*)(ws + 32505856);      // 31 MB  .. 39 MB

  // 1) all fp32->bf16 converts in one launch
  cvt_all<<<(N4_X + N4_WQ + N4_WO) / 256, 256, 0, stream>>>(
      x, w_qkv, w_out, xb, wqkvb, woutb);

  // 2) QKV GEMM + fused rope/scale/pack (single-wave blocks, 1536 of them)
  gemm_qkv<<<dim3(NB * NT / 64, QKVD / 64), 64, 0, stream>>>(
      xb, wqkvb, cosT, sinT, q_scale, k_scale, qb, kb, vtb);

  // 3) flash attention (r7: swapped-QK in-lane softmax; 1536 blocks)
  fattn<<<dim3(48, NHEADS, NB), 256, 0, stream>>>(qb, kb, vtb, aob, pbuf);
  redn<<<dim3(16, NHEADS, NB), 256, 0, stream>>>(pbuf, vtb, aob);

  // 4) out = ao @ w_out^T (single-wave blocks, 1024 of them)
  gemm_out<<<dim3(NB * NT / 64, ND / 64), 64, 0, stream>>>(
      aob, woutb, out, NB * NT, ND, ND);
}